// Round 7
// baseline (301.639 us; speedup 1.0000x reference)
//
#include <hip/hip_runtime.h>
#include <hip/hip_bf16.h>
#include <stdint.h>

#define NN 100000
#define NE 1600000
#define NR (NE + NN)   // records incl. self-loops
#define DD 128
#define NEG 0.01f
#define NB 391        // buckets of 256 nodes (dst>>8); ceil(NN/256)
#define CAPSH 13      // 8192 pair slots per bucket (mean 4096 + 64 sigma)
#define NBLKE 391     // ceil(NE/4096) edge blocks (8 edges/thread @512)
#define NWB 65        // weight-pack rider blocks (33024/512 rounded up)
#define GPAD 16       // gcur stride in ints: one counter per 64B line

typedef __attribute__((ext_vector_type(8))) short short8;
typedef __attribute__((ext_vector_type(4))) float floatx4;
typedef __attribute__((ext_vector_type(4))) uint32_t uint32x4;

__device__ __forceinline__ uint16_t f2bf(float f){
  uint32_t i = __float_as_uint(f);
  return (uint16_t)((i + 0x7FFFu + ((i >> 16) & 1u)) >> 16);  // RNE
}
__device__ __forceinline__ float lrelu(float x){ return fmaxf(x, NEG * x); }

// ---------------- init: dtype detect + zero padded bucket cursors -------------
__global__ __launch_bounds__(512) void k_init(const uint32_t* __restrict__ xw,
                                              int* __restrict__ flag,
                                              int* __restrict__ gcur){
  int t = threadIdx.x;
  for (int i = t; i < NB * GPAD; i += 512) gcur[i] = 0;
  if (t < 64){
    uint32_t w = xw[t];
    uint32_t e = (w >> 7) & 0xFFu;
    int plaus = (e >= 100u && e <= 134u) ? 1 : 0;
    unsigned long long b = __ballot(plaus);
    if (t == 0) flag[0] = (__popcll(b) >= 48) ? 0 : 1;
  }
}

// ---------------- bucket scatter (one pass) + weight-pack rider blocks --------
__global__ __launch_bounds__(512) void k_scat1(const int* __restrict__ src,
                                               const int* __restrict__ dst,
                                               int* __restrict__ gcur,
                                               uint32_t* __restrict__ pairs,
                                               const void* __restrict__ W1,
                                               const void* __restrict__ W2,
                                               const void* __restrict__ b1,
                                               const void* __restrict__ b2,
                                               uint16_t* __restrict__ WT1,
                                               uint16_t* __restrict__ WT2,
                                               uint16_t* __restrict__ bb,
                                               const int* __restrict__ flag){
  int t = threadIdx.x, b = blockIdx.x;
  if (b >= NBLKE){   // weight transpose + bias pack riders
    int j = (b - NBLKE) * 512 + t;
    int f = flag[0];
    if (j < 16384){
      int c = j >> 7, k = j & 127;
      WT1[j] = f ? f2bf(((const float*)W1)[k * DD + c])
                 : ((const uint16_t*)W1)[k * DD + c];
    } else if (j < 32768){
      int q = j - 16384;
      int c = q >> 7, k = q & 127;
      WT2[q] = f ? f2bf(((const float*)W2)[k * DD + c])
                 : ((const uint16_t*)W2)[k * DD + c];
    } else if (j < 33024){
      int q = j - 32768;
      const void* sp = (q < 128) ? b1 : b2;
      int i2 = q & 127;
      bb[q] = f ? f2bf(((const float*)sp)[i2]) : ((const uint16_t*)sp)[i2];
    }
    return;
  }
  __shared__ int lh[NB];
  if (t < NB) lh[t] = 0;
  __syncthreads();
  int ds[8], ss[8];
  #pragma unroll
  for (int i = 0; i < 8; i++){
    int e = b * 4096 + i * 512 + t;
    if (e < NE){
      ds[i] = dst[e]; ss[i] = src[e];
      atomicAdd(&lh[ds[i] >> 8], 1);
    } else ds[i] = -1;
  }
  __syncthreads();
  if (t < NB){
    int c = lh[t];
    int base = c ? atomicAdd(&gcur[t * GPAD], c) : 0;
    lh[t] = (t << CAPSH) + base;        // block-local cursor = global slot
  }
  __syncthreads();
  #pragma unroll
  for (int i = 0; i < 8; i++){
    if (ds[i] >= 0){
      int bkt = ds[i] >> 8;
      int pos = atomicAdd(&lh[bkt], 1);
      if (pos < ((bkt + 1) << CAPSH))   // cap guard (never fires on 16-sigma input)
        pairs[pos] = ((uint32_t)(ds[i] & 255) << 24) | (uint32_t)ss[i];
    }
  }
}

// ---------------- bsort_a: per-node counts -> prow, dis, self records ---------
__global__ __launch_bounds__(512) void k_bsort_a(const uint32_t* __restrict__ pairs,
                                                 const int* __restrict__ gcur,
                                                 int2* __restrict__ pairs2,
                                                 int* __restrict__ prow,
                                                 float* __restrict__ dis){
  __shared__ int sg[512];
  __shared__ int lcnt[256], sm[256];
  __shared__ int s_pe;
  int t = threadIdx.x, bkt = blockIdx.x, n0 = bkt << 8;
  int v0 = (t < NB) ? gcur[t * GPAD] : 0;
  sg[t] = v0;
  __syncthreads();
  for (int s = 1; s < 512; s <<= 1){
    int add = (t >= s) ? sg[t - s] : 0;
    __syncthreads();
    sg[t] += add;
    __syncthreads();
  }
  if (t == bkt) s_pe = sg[t] - v0;      // edges in buckets before this one
  if (t < 256) lcnt[t] = 0;
  __syncthreads();
  int cnt = gcur[bkt * GPAD];
  int begE = bkt << CAPSH;
  for (int i = t; i < cnt; i += 512)
    atomicAdd(&lcnt[pairs[begE + i] >> 24], 1);
  __syncthreads();
  int inb = (n0 + t < NN) ? 1 : 0;
  int v = (t < 256) ? lcnt[t] + inb : 0;
  if (t < 256) sm[t] = v;
  __syncthreads();
  for (int s = 1; s < 256; s <<= 1){
    int add = (t < 256 && t >= s) ? sm[t - s] : 0;
    __syncthreads();
    if (t < 256) sm[t] += add;
    __syncthreads();
  }
  if (t < 256){
    int n = n0 + t;
    int begS = s_pe + n0;               // + one self slot per preceding node
    int excl = sm[t] - v;
    if (n <= NN) prow[n] = begS + excl; // n==NN (bkt 390, t=160) -> prow[NN]=NR
    if (n < NN){
      float dn = rsqrtf((float)(lcnt[t] + 1));
      dis[n] = dn;
      pairs2[begS + excl] = make_int2(n, __float_as_int(dn * dn));  // self, final
    }
  }
}

// ---------------- bsort_b: re-scatter with final coef dis[d]*dis[s] -----------
__global__ __launch_bounds__(512) void k_bsort_b(const uint32_t* __restrict__ pairs,
                                                 const int* __restrict__ gcur,
                                                 const int* __restrict__ prow,
                                                 const float* __restrict__ dis,
                                                 int2* __restrict__ pairs2){
  __shared__ int cur[256];
  __shared__ float ddn[256];
  int t = threadIdx.x, bkt = blockIdx.x, n0 = bkt << 8;
  if (t < 256){
    int n = n0 + t;
    cur[t] = (n < NN) ? prow[n] + 1 : 0;   // first edge slot (after self)
    ddn[t] = (n < NN) ? dis[n] : 0.f;
  }
  __syncthreads();
  int cnt = gcur[bkt * GPAD];
  int begE = bkt << CAPSH;
  for (int i = t; i < cnt; i += 512){
    uint32_t u = pairs[begE + i];
    int li = u >> 24, s = (int)(u & 0xFFFFFFu);
    int pos = atomicAdd(&cur[li], 1);
    pairs2[pos] = make_int2(s, __float_as_int(ddn[li] * dis[s]));
  }
}

__device__ __forceinline__ short8 ldcvt(const float* __restrict__ p){
  floatx4 u = ((const floatx4*)p)[0], v = ((const floatx4*)p)[1];
  short8 r;
  r[0] = (short)f2bf(u.x); r[1] = (short)f2bf(u.y);
  r[2] = (short)f2bf(u.z); r[3] = (short)f2bf(u.w);
  r[4] = (short)f2bf(v.x); r[5] = (short)f2bf(v.y);
  r[6] = (short)f2bf(v.z); r[7] = (short)f2bf(v.w);
  return r;
}

// ---------------- GEMM (layer 1): H1 = X * W1, optional f32 input -------------
__global__ __launch_bounds__(256) void k_gemm(const void* __restrict__ X,
                                              const uint16_t* __restrict__ WT,
                                              uint16_t* __restrict__ H,
                                              const int* __restrict__ flag,
                                              int xf32){
  __shared__ uint16_t lwt[128 * 136];   // +8 shorts pad -> 2-way bank alias (free)
  int t = threadIdx.x;
  const uint32_t* wt32 = (const uint32_t*)WT;
  #pragma unroll
  for (int i = 0; i < 32; i++){
    int uidx = t + 256 * i;
    uint32_t w2 = wt32[uidx];
    int el = uidx * 2;
    int c = el >> 7, k = el & 127;
    *(uint32_t*)&lwt[c * 136 + k] = w2;
  }
  __syncthreads();

  int wave = t >> 6, lane = t & 63;
  int m = lane & 15, q = lane >> 4;
  int rowbase = blockIdx.x * 64 + wave * 16;
  int ar = rowbase + m;
  if (ar >= NN) ar = 0;
  short8 a0, a1, a2, a3;
  if (xf32 && flag[0]){
    const float* xr = (const float*)X + (size_t)ar * DD;
    a0 = ldcvt(xr + q * 8);        a1 = ldcvt(xr + (q + 4) * 8);
    a2 = ldcvt(xr + (q + 8) * 8);  a3 = ldcvt(xr + (q + 12) * 8);
  } else {
    const short8* xrow = (const short8*)((const uint16_t*)X + (size_t)ar * DD);
    a0 = xrow[q]; a1 = xrow[q + 4]; a2 = xrow[q + 8]; a3 = xrow[q + 12];
  }

  #pragma unroll
  for (int nt = 0; nt < 8; nt++){
    int c = nt * 16 + m;
    const uint16_t* bp = &lwt[c * 136 + q * 8];
    floatx4 acc = {0.f, 0.f, 0.f, 0.f};
    acc = __builtin_amdgcn_mfma_f32_16x16x32_bf16(a0, *(const short8*)(bp +  0), acc, 0, 0, 0);
    acc = __builtin_amdgcn_mfma_f32_16x16x32_bf16(a1, *(const short8*)(bp + 32), acc, 0, 0, 0);
    acc = __builtin_amdgcn_mfma_f32_16x16x32_bf16(a2, *(const short8*)(bp + 64), acc, 0, 0, 0);
    acc = __builtin_amdgcn_mfma_f32_16x16x32_bf16(a3, *(const short8*)(bp + 96), acc, 0, 0, 0);
    #pragma unroll
    for (int r = 0; r < 4; r++){
      int row = rowbase + q * 4 + r;
      if (row < NN) H[(size_t)row * DD + c] = f2bf(acc[r]);
    }
  }
}

#define FMA8(VA, CF)                                                     \
  acc[0] = fmaf(__uint_as_float(VA.x << 16),         CF, acc[0]);        \
  acc[1] = fmaf(__uint_as_float(VA.x & 0xffff0000u), CF, acc[1]);        \
  acc[2] = fmaf(__uint_as_float(VA.y << 16),         CF, acc[2]);        \
  acc[3] = fmaf(__uint_as_float(VA.y & 0xffff0000u), CF, acc[3]);        \
  acc[4] = fmaf(__uint_as_float(VA.z << 16),         CF, acc[4]);        \
  acc[5] = fmaf(__uint_as_float(VA.z & 0xffff0000u), CF, acc[5]);        \
  acc[6] = fmaf(__uint_as_float(VA.w << 16),         CF, acc[6]);        \
  acc[7] = fmaf(__uint_as_float(VA.w & 0xffff0000u), CF, acc[7]);

// ---------------- fused agg1 + gemm2: 16 nodes/block, epilogue MFMA -----------
// 4 waves x 4 serial nodes each (gather loop UNCHANGED from the frozen k_agg);
// lrelu'd layer-1 rows land in a 16x128 LDS tile, then the block computes
// H2 = tile * W2 with 16x16x32 MFMA (B-frags read from L2-resident WT2).
// Deletes the hB write + read round-trip and the separate gemm2 dispatch.
__global__ __launch_bounds__(256) void k_aggg(const uint16_t* __restrict__ H,
                                              const int* __restrict__ prow,
                                              const int2* __restrict__ pairs2,
                                              const uint16_t* __restrict__ bias,
                                              const uint16_t* __restrict__ WT2,
                                              uint16_t* __restrict__ H2){
  __shared__ int2 ebuf[4][96];          // [wave][64 live + 32 zero-pad]
  __shared__ uint16_t hrow[16 * 136];   // 16x128 A-tile, 136-stride (aligned 16B)
  int wave = threadIdx.x >> 6, lane = threadIdx.x & 63;
  int grp = lane >> 4, sl = lane & 15;
  if (lane >= 32) ebuf[wave][32 + lane] = make_int2(0, 0);
  int tile = blockIdx.x << 4;           // 6250 * 16 == NN exactly, no tail
  uint32x4 bv = ((const uint32x4*)bias)[sl];

  for (int i = 0; i < 4; i++){
    int n = tile + wave * 4 + i;
    int beg = prow[n], end = prow[n + 1];
    float acc[8] = {0.f,0.f,0.f,0.f,0.f,0.f,0.f,0.f};
    for (int j0 = beg; j0 < end; j0 += 64){
      int cnt = min(64, end - j0);
      int2 r = (lane < cnt) ? pairs2[j0 + lane] : make_int2(0, 0);
      ebuf[wave][lane] = r;
      int chunks = (cnt + 3) >> 2;
      int2 e0 = ebuf[wave][grp];
      int2 e1 = ebuf[wave][4 + grp];
      int2 e2 = ebuf[wave][8 + grp];
      uint32x4 v0 = *(const uint32x4*)(H + (size_t)e0.x * DD + sl * 8);
      uint32x4 v1 = *(const uint32x4*)(H + (size_t)e1.x * DD + sl * 8);
      uint32x4 v2 = *(const uint32x4*)(H + (size_t)e2.x * DD + sl * 8);
      for (int c = 0; c < chunks; c += 3){
        int2 n0 = ebuf[wave][(c + 3) * 4 + grp];
        int2 n1 = ebuf[wave][(c + 4) * 4 + grp];
        int2 n2 = ebuf[wave][(c + 5) * 4 + grp];
        uint32x4 w0 = *(const uint32x4*)(H + (size_t)n0.x * DD + sl * 8);
        uint32x4 w1 = *(const uint32x4*)(H + (size_t)n1.x * DD + sl * 8);
        uint32x4 w2 = *(const uint32x4*)(H + (size_t)n2.x * DD + sl * 8);
        float c0 = __int_as_float(e0.y);
        FMA8(v0, c0)
        float c1 = __int_as_float(e1.y);
        FMA8(v1, c1)
        float c2 = __int_as_float(e2.y);
        FMA8(v2, c2)
        e0 = n0; e1 = n1; e2 = n2;
        v0 = w0; v1 = w1; v2 = w2;
      }
    }
    #pragma unroll
    for (int j = 0; j < 8; j++){
      acc[j] += __shfl_xor(acc[j], 16, 64);
      acc[j] += __shfl_xor(acc[j], 32, 64);
    }
    float o0 = lrelu(acc[0] + __uint_as_float(bv.x << 16));
    float o1 = lrelu(acc[1] + __uint_as_float(bv.x & 0xffff0000u));
    float o2 = lrelu(acc[2] + __uint_as_float(bv.y << 16));
    float o3 = lrelu(acc[3] + __uint_as_float(bv.y & 0xffff0000u));
    float o4 = lrelu(acc[4] + __uint_as_float(bv.z << 16));
    float o5 = lrelu(acc[5] + __uint_as_float(bv.z & 0xffff0000u));
    float o6 = lrelu(acc[6] + __uint_as_float(bv.w << 16));
    float o7 = lrelu(acc[7] + __uint_as_float(bv.w & 0xffff0000u));
    if (lane < 16){
      uint32x4 pv;
      pv.x = (uint32_t)f2bf(o0) | ((uint32_t)f2bf(o1) << 16);
      pv.y = (uint32_t)f2bf(o2) | ((uint32_t)f2bf(o3) << 16);
      pv.z = (uint32_t)f2bf(o4) | ((uint32_t)f2bf(o5) << 16);
      pv.w = (uint32_t)f2bf(o6) | ((uint32_t)f2bf(o7) << 16);
      *(uint32x4*)&hrow[(wave * 4 + i) * 136 + sl * 8] = pv;
    }
  }
  __syncthreads();

  // GEMM epilogue: C[16x128] = hrow[16x128] * W2; wave handles 2 column-tiles.
  int m = lane & 15, q = lane >> 4;
  short8 a0 = *(const short8*)&hrow[m * 136 + q * 8];
  short8 a1 = *(const short8*)&hrow[m * 136 + (q + 4) * 8];
  short8 a2 = *(const short8*)&hrow[m * 136 + (q + 8) * 8];
  short8 a3 = *(const short8*)&hrow[m * 136 + (q + 12) * 8];
  #pragma unroll
  for (int nt = 0; nt < 2; nt++){
    int c = (wave * 2 + nt) * 16 + m;
    const uint16_t* bp = WT2 + c * DD + q * 8;
    floatx4 a2c = {0.f, 0.f, 0.f, 0.f};
    a2c = __builtin_amdgcn_mfma_f32_16x16x32_bf16(a0, *(const short8*)(bp +  0), a2c, 0, 0, 0);
    a2c = __builtin_amdgcn_mfma_f32_16x16x32_bf16(a1, *(const short8*)(bp + 32), a2c, 0, 0, 0);
    a2c = __builtin_amdgcn_mfma_f32_16x16x32_bf16(a2, *(const short8*)(bp + 64), a2c, 0, 0, 0);
    a2c = __builtin_amdgcn_mfma_f32_16x16x32_bf16(a3, *(const short8*)(bp + 96), a2c, 0, 0, 0);
    #pragma unroll
    for (int r = 0; r < 4; r++)
      H2[(size_t)(tile + q * 4 + r) * DD + c] = f2bf(a2c[r]);
  }
}

// ---------------- final aggregation (layer 2) -- frozen ----------------------
__global__ __launch_bounds__(256) void k_agg(const uint16_t* __restrict__ H,
                                             const int* __restrict__ prow,
                                             const int2* __restrict__ pairs2,
                                             const uint16_t* __restrict__ bias,
                                             void* __restrict__ OUT,
                                             const int* __restrict__ flag,
                                             int is_final){
  __shared__ int2 ebuf[4][96];   // [wave][64 live + 32 zero-pad]
  int wave = threadIdx.x >> 6, lane = threadIdx.x & 63;
  int grp = lane >> 4, sl = lane & 15;
  if (lane >= 32) ebuf[wave][32 + lane] = make_int2(0, 0);  // pad slots 64..95
  int n = blockIdx.x * 4 + wave;
  if (n >= NN) return;
  int beg = prow[n], end = prow[n + 1];

  float acc[8] = {0.f,0.f,0.f,0.f,0.f,0.f,0.f,0.f};
  for (int j0 = beg; j0 < end; j0 += 64){
    int cnt = min(64, end - j0);
    int2 r = (lane < cnt) ? pairs2[j0 + lane] : make_int2(0, 0);
    ebuf[wave][lane] = r;
    int chunks = (cnt + 3) >> 2;
    int2 e0 = ebuf[wave][grp];
    int2 e1 = ebuf[wave][4 + grp];
    int2 e2 = ebuf[wave][8 + grp];
    uint32x4 v0 = *(const uint32x4*)(H + (size_t)e0.x * DD + sl * 8);
    uint32x4 v1 = *(const uint32x4*)(H + (size_t)e1.x * DD + sl * 8);
    uint32x4 v2 = *(const uint32x4*)(H + (size_t)e2.x * DD + sl * 8);
    for (int c = 0; c < chunks; c += 3){
      int2 n0 = ebuf[wave][(c + 3) * 4 + grp];
      int2 n1 = ebuf[wave][(c + 4) * 4 + grp];
      int2 n2 = ebuf[wave][(c + 5) * 4 + grp];
      uint32x4 w0 = *(const uint32x4*)(H + (size_t)n0.x * DD + sl * 8);
      uint32x4 w1 = *(const uint32x4*)(H + (size_t)n1.x * DD + sl * 8);
      uint32x4 w2 = *(const uint32x4*)(H + (size_t)n2.x * DD + sl * 8);
      float c0 = __int_as_float(e0.y);
      FMA8(v0, c0)
      float c1 = __int_as_float(e1.y);
      FMA8(v1, c1)
      float c2 = __int_as_float(e2.y);
      FMA8(v2, c2)
      e0 = n0; e1 = n1; e2 = n2;
      v0 = w0; v1 = w1; v2 = w2;
    }
  }
  #pragma unroll
  for (int j = 0; j < 8; j++){
    acc[j] += __shfl_xor(acc[j], 16, 64);
    acc[j] += __shfl_xor(acc[j], 32, 64);
  }
  uint32x4 bv = ((const uint32x4*)bias)[sl];
  float o0 = lrelu(acc[0] + __uint_as_float(bv.x << 16));
  float o1 = lrelu(acc[1] + __uint_as_float(bv.x & 0xffff0000u));
  float o2 = lrelu(acc[2] + __uint_as_float(bv.y << 16));
  float o3 = lrelu(acc[3] + __uint_as_float(bv.y & 0xffff0000u));
  float o4 = lrelu(acc[4] + __uint_as_float(bv.z << 16));
  float o5 = lrelu(acc[5] + __uint_as_float(bv.z & 0xffff0000u));
  float o6 = lrelu(acc[6] + __uint_as_float(bv.w << 16));
  float o7 = lrelu(acc[7] + __uint_as_float(bv.w & 0xffff0000u));
  if (is_final && flag[0]){
    float* orow = (float*)OUT + (size_t)n * DD + sl * 8;
    if (lane < 16){ floatx4 vv = {o0, o1, o2, o3}; ((floatx4*)orow)[0] = vv; }
    else if (lane < 32){ floatx4 vv = {o4, o5, o6, o7}; ((floatx4*)orow)[1] = vv; }
  } else if (lane < 16){
    uint32x4 pv;
    pv.x = (uint32_t)f2bf(o0) | ((uint32_t)f2bf(o1) << 16);
    pv.y = (uint32_t)f2bf(o2) | ((uint32_t)f2bf(o3) << 16);
    pv.z = (uint32_t)f2bf(o4) | ((uint32_t)f2bf(o5) << 16);
    pv.w = (uint32_t)f2bf(o6) | ((uint32_t)f2bf(o7) << 16);
    *(uint32x4*)((uint16_t*)OUT + (size_t)n * DD + sl * 8) = pv;
  }
}

extern "C" void kernel_launch(void* const* d_in, const int* in_sizes, int n_in,
                              void* d_out, int out_size, void* d_ws, size_t ws_size,
                              hipStream_t stream){
  const void* x  = d_in[0];
  const void* W1 = d_in[1];
  const void* b1 = d_in[2];
  const void* W2 = d_in[3];
  const void* b2 = d_in[4];
  const int* ei   = (const int*)d_in[5];
  const int* esrc = ei;
  const int* edst = ei + NE;

  char* ws = (char*)d_ws;
  float*    dis        = (float*)(ws + 0);                     // 400,000 B
  int*      prow       = (int*)(ws + 512ull * 1024);           // 400,004 B
  int*      flag       = (int*)(ws + 960ull * 1024);           // 4 B
  uint16_t* WT1        = (uint16_t*)(ws + 964ull * 1024);      // 32 KiB
  uint16_t* WT2        = (uint16_t*)(ws + 996ull * 1024);      // 32 KiB
  uint16_t* bb         = (uint16_t*)(ws + 1028ull * 1024);     // 512 B
  int*      gcur       = (int*)(ws + 1032ull * 1024);          // 25,024 B (padded)
  int2*     pairs2     = (int2*)(ws + 2048ull * 1024);         // 13.6 MB
  uint32_t* pairs      = (uint32_t*)(ws + 16320ull * 1024);    // 6.4 MB (dead pre-aggg)
  uint16_t* hA         = (uint16_t*)(ws + 16384ull * 1024);    // 25.6 MB: H2 (aliases pairs)
  uint16_t* hB         = (uint16_t*)d_out;                     // H1 scratch; agg2 overwrites

  k_init   <<<1, 512, 0, stream>>>((const uint32_t*)x, flag, gcur);
  k_scat1  <<<NBLKE + NWB, 512, 0, stream>>>(esrc, edst, gcur, pairs,
                                             W1, W2, b1, b2, WT1, WT2, bb, flag);
  k_bsort_a<<<NB, 512, 0, stream>>>(pairs, gcur, pairs2, prow, dis);
  k_bsort_b<<<NB, 512, 0, stream>>>(pairs, gcur, prow, dis, pairs2);

  k_gemm<<<(NN + 63) / 64, 256, 0, stream>>>(x, WT1, hB, flag, 1);      // H1 -> d_out
  k_aggg<<<NN / 16, 256, 0, stream>>>(hB, prow, pairs2, bb, WT2, hA);   // agg1+gemm2 -> H2
  k_agg <<<NN / 4, 256, 0, stream>>>(hA, prow, pairs2, bb + 128, d_out, flag, 1);
}

// Round 8
// 300.544 us; speedup vs baseline: 1.0036x; 1.0036x over previous
//
#include <hip/hip_runtime.h>
#include <hip/hip_bf16.h>
#include <stdint.h>

#define NN 100000
#define NE 1600000
#define NR (NE + NN)   // records incl. self-loops
#define DD 128
#define NEG 0.01f
#define NB 391        // buckets of 256 nodes (dst>>8); ceil(NN/256)
#define CAPSH 13      // 8192 pair slots per bucket (mean 4096 + 64 sigma)
#define NBLKE 391     // ceil(NE/4096) edge blocks (8 edges/thread @512)
#define NWB 65        // weight-pack rider blocks (33024/512 rounded up)
#define GPAD 16       // gcur stride in ints: one counter per 64B line
#define PADROW (-256) // pad record: zero row at H - 256*DD (ws+16320KiB, dead pairs area)

typedef __attribute__((ext_vector_type(8))) short short8;
typedef __attribute__((ext_vector_type(4))) float floatx4;
typedef __attribute__((ext_vector_type(4))) uint32_t uint32x4;

__device__ __forceinline__ uint16_t f2bf(float f){
  uint32_t i = __float_as_uint(f);
  return (uint16_t)((i + 0x7FFFu + ((i >> 16) & 1u)) >> 16);  // RNE
}
__device__ __forceinline__ float lrelu(float x){ return fmaxf(x, NEG * x); }

// ---------------- init: dtype detect + zero padded bucket cursors -------------
__global__ __launch_bounds__(512) void k_init(const uint32_t* __restrict__ xw,
                                              int* __restrict__ flag,
                                              int* __restrict__ gcur){
  int t = threadIdx.x;
  for (int i = t; i < NB * GPAD; i += 512) gcur[i] = 0;
  if (t < 64){
    uint32_t w = xw[t];
    uint32_t e = (w >> 7) & 0xFFu;
    int plaus = (e >= 100u && e <= 134u) ? 1 : 0;
    unsigned long long b = __ballot(plaus);
    if (t == 0) flag[0] = (__popcll(b) >= 48) ? 0 : 1;
  }
}

// ---------------- bucket scatter (one pass) + weight-pack rider blocks --------
// Records packed {dlow:8 | src:24}; per-(block,bucket) contiguous runs (R2 lesson).
__global__ __launch_bounds__(512) void k_scat1(const int* __restrict__ src,
                                               const int* __restrict__ dst,
                                               int* __restrict__ gcur,
                                               uint32_t* __restrict__ pairs,
                                               const void* __restrict__ W1,
                                               const void* __restrict__ W2,
                                               const void* __restrict__ b1,
                                               const void* __restrict__ b2,
                                               uint16_t* __restrict__ WT1,
                                               uint16_t* __restrict__ WT2,
                                               uint16_t* __restrict__ bb,
                                               const int* __restrict__ flag){
  int t = threadIdx.x, b = blockIdx.x;
  if (b >= NBLKE){   // weight transpose + bias pack riders
    int j = (b - NBLKE) * 512 + t;
    int f = flag[0];
    if (j < 16384){
      int c = j >> 7, k = j & 127;
      WT1[j] = f ? f2bf(((const float*)W1)[k * DD + c])
                 : ((const uint16_t*)W1)[k * DD + c];
    } else if (j < 32768){
      int q = j - 16384;
      int c = q >> 7, k = q & 127;
      WT2[q] = f ? f2bf(((const float*)W2)[k * DD + c])
                 : ((const uint16_t*)W2)[k * DD + c];
    } else if (j < 33024){
      int q = j - 32768;
      const void* sp = (q < 128) ? b1 : b2;
      int i2 = q & 127;
      bb[q] = f ? f2bf(((const float*)sp)[i2]) : ((const uint16_t*)sp)[i2];
    }
    return;
  }
  __shared__ int lh[NB];
  if (t < NB) lh[t] = 0;
  __syncthreads();
  int ds[8], ss[8];
  #pragma unroll
  for (int i = 0; i < 8; i++){
    int e = b * 4096 + i * 512 + t;
    if (e < NE){
      ds[i] = dst[e]; ss[i] = src[e];
      atomicAdd(&lh[ds[i] >> 8], 1);
    } else ds[i] = -1;
  }
  __syncthreads();
  if (t < NB){
    int c = lh[t];
    int base = c ? atomicAdd(&gcur[t * GPAD], c) : 0;
    lh[t] = (t << CAPSH) + base;        // block-local cursor = global slot
  }
  __syncthreads();
  #pragma unroll
  for (int i = 0; i < 8; i++){
    if (ds[i] >= 0){
      int bkt = ds[i] >> 8;
      int pos = atomicAdd(&lh[bkt], 1);
      if (pos < ((bkt + 1) << CAPSH))   // cap guard (never fires on 16-sigma input)
        pairs[pos] = ((uint32_t)(ds[i] & 255) << 24) | (uint32_t)ss[i];
    }
  }
}

// ---------------- bsort_a: per-node counts -> prow, dis, self records ---------
// Records are now BARE src indices (no coef: H rows are pre-scaled by dn_src
// in the GEMM epilogue; dn_dst applied in the agg epilogue).
__global__ __launch_bounds__(512) void k_bsort_a(const uint32_t* __restrict__ pairs,
                                                 const int* __restrict__ gcur,
                                                 int* __restrict__ pairs2,
                                                 int* __restrict__ prow,
                                                 float* __restrict__ dis){
  __shared__ int sg[512];
  __shared__ int lcnt[256], sm[256];
  __shared__ int s_pe;
  int t = threadIdx.x, bkt = blockIdx.x, n0 = bkt << 8;
  int v0 = (t < NB) ? gcur[t * GPAD] : 0;
  sg[t] = v0;
  __syncthreads();
  for (int s = 1; s < 512; s <<= 1){
    int add = (t >= s) ? sg[t - s] : 0;
    __syncthreads();
    sg[t] += add;
    __syncthreads();
  }
  if (t == bkt) s_pe = sg[t] - v0;      // edges in buckets before this one
  if (t < 256) lcnt[t] = 0;
  __syncthreads();
  int cnt = gcur[bkt * GPAD];
  int begE = bkt << CAPSH;
  for (int i = t; i < cnt; i += 512)
    atomicAdd(&lcnt[pairs[begE + i] >> 24], 1);
  __syncthreads();
  int inb = (n0 + t < NN) ? 1 : 0;
  int v = (t < 256) ? lcnt[t] + inb : 0;
  if (t < 256) sm[t] = v;
  __syncthreads();
  for (int s = 1; s < 256; s <<= 1){
    int add = (t < 256 && t >= s) ? sm[t - s] : 0;
    __syncthreads();
    if (t < 256) sm[t] += add;
    __syncthreads();
  }
  if (t < 256){
    int n = n0 + t;
    int begS = s_pe + n0;               // + one self slot per preceding node
    int excl = sm[t] - v;
    if (n <= NN) prow[n] = begS + excl; // n==NN (bkt 390, t=160) -> prow[NN]=NR
    if (n < NN){
      dis[n] = rsqrtf((float)(lcnt[t] + 1));
      pairs2[begS + excl] = n;          // self record: just the index
    }
  }
}

// ---------------- bsort_b: re-scatter bare src (NO dis gather anymore) --------
__global__ __launch_bounds__(512) void k_bsort_b(const uint32_t* __restrict__ pairs,
                                                 const int* __restrict__ gcur,
                                                 const int* __restrict__ prow,
                                                 int* __restrict__ pairs2){
  __shared__ int cur[256];
  int t = threadIdx.x, bkt = blockIdx.x, n0 = bkt << 8;
  if (t < 256){
    int n = n0 + t;
    cur[t] = (n < NN) ? prow[n] + 1 : 0;   // first edge slot (after self)
  }
  __syncthreads();
  int cnt = gcur[bkt * GPAD];
  int begE = bkt << CAPSH;
  for (int i = t; i < cnt; i += 512){
    uint32_t u = pairs[begE + i];
    int li = u >> 24;
    int pos = atomicAdd(&cur[li], 1);
    pairs2[pos] = (int)(u & 0xFFFFFFu);
  }
}

__device__ __forceinline__ short8 ldcvt(const float* __restrict__ p){
  floatx4 u = ((const floatx4*)p)[0], v = ((const floatx4*)p)[1];
  short8 r;
  r[0] = (short)f2bf(u.x); r[1] = (short)f2bf(u.y);
  r[2] = (short)f2bf(u.z); r[3] = (short)f2bf(u.w);
  r[4] = (short)f2bf(v.x); r[5] = (short)f2bf(v.y);
  r[6] = (short)f2bf(v.z); r[7] = (short)f2bf(v.w);
  return r;
}

// ---------------- GEMM: Hs = dn[row] * (X * W) (pre-scaled rows) --------------
// Block 0 also zeroes the pad row at H - 256*DD (dead pairs area) so agg's
// pipeline over-reads (record PADROW) contribute exactly 0.
__global__ __launch_bounds__(256) void k_gemm(const void* __restrict__ X,
                                              const uint16_t* __restrict__ WT,
                                              uint16_t* __restrict__ H,
                                              const int* __restrict__ flag,
                                              int xf32,
                                              const float* __restrict__ dis){
  __shared__ uint16_t lwt[128 * 136];   // +8 shorts pad -> 2-way bank alias (free)
  int t = threadIdx.x;
  if (blockIdx.x == 0 && t < 16){
    uint32x4 z = {0u, 0u, 0u, 0u};
    *(uint32x4*)(H + (ptrdiff_t)PADROW * DD + t * 8) = z;
  }
  const uint32_t* wt32 = (const uint32_t*)WT;
  #pragma unroll
  for (int i = 0; i < 32; i++){
    int uidx = t + 256 * i;
    uint32_t w2 = wt32[uidx];
    int el = uidx * 2;
    int c = el >> 7, k = el & 127;
    *(uint32_t*)&lwt[c * 136 + k] = w2;
  }
  __syncthreads();

  int wave = t >> 6, lane = t & 63;
  int m = lane & 15, q = lane >> 4;
  int rowbase = blockIdx.x * 64 + wave * 16;
  int ar = rowbase + m;
  if (ar >= NN) ar = 0;
  short8 a0, a1, a2, a3;
  if (xf32 && flag[0]){
    const float* xr = (const float*)X + (size_t)ar * DD;
    a0 = ldcvt(xr + q * 8);        a1 = ldcvt(xr + (q + 4) * 8);
    a2 = ldcvt(xr + (q + 8) * 8);  a3 = ldcvt(xr + (q + 12) * 8);
  } else {
    const short8* xrow = (const short8*)((const uint16_t*)X + (size_t)ar * DD);
    a0 = xrow[q]; a1 = xrow[q + 4]; a2 = xrow[q + 8]; a3 = xrow[q + 12];
  }
  float dnr[4];
  #pragma unroll
  for (int r = 0; r < 4; r++){
    int row = rowbase + q * 4 + r;
    dnr[r] = dis[(row < NN) ? row : 0];
  }

  #pragma unroll
  for (int nt = 0; nt < 8; nt++){
    int c = nt * 16 + m;
    const uint16_t* bp = &lwt[c * 136 + q * 8];
    floatx4 acc = {0.f, 0.f, 0.f, 0.f};
    acc = __builtin_amdgcn_mfma_f32_16x16x32_bf16(a0, *(const short8*)(bp +  0), acc, 0, 0, 0);
    acc = __builtin_amdgcn_mfma_f32_16x16x32_bf16(a1, *(const short8*)(bp + 32), acc, 0, 0, 0);
    acc = __builtin_amdgcn_mfma_f32_16x16x32_bf16(a2, *(const short8*)(bp + 64), acc, 0, 0, 0);
    acc = __builtin_amdgcn_mfma_f32_16x16x32_bf16(a3, *(const short8*)(bp + 96), acc, 0, 0, 0);
    #pragma unroll
    for (int r = 0; r < 4; r++){
      int row = rowbase + q * 4 + r;
      if (row < NN) H[(size_t)row * DD + c] = f2bf(acc[r] * dnr[r]);
    }
  }
}

#define ADD8(VA)                                          \
  acc[0] += __uint_as_float(VA.x << 16);                  \
  acc[1] += __uint_as_float(VA.x & 0xffff0000u);          \
  acc[2] += __uint_as_float(VA.y << 16);                  \
  acc[3] += __uint_as_float(VA.y & 0xffff0000u);          \
  acc[4] += __uint_as_float(VA.z << 16);                  \
  acc[5] += __uint_as_float(VA.z & 0xffff0000u);          \
  acc[6] += __uint_as_float(VA.w << 16);                  \
  acc[7] += __uint_as_float(VA.w & 0xffff0000u);

// ---------------- aggregation: ONE node/wave (frozen recipe), bare-int recs ---
// out[n] = lrelu(dn[n] * sum(Hs[rec]) + bias). Records have no coef; pad
// records = PADROW (zero row). Gather pattern/TLP identical to the proven 3.9
// TB/s recipe (R7 lesson: serial-nodes-per-wave drops the serving rate).
__global__ __launch_bounds__(256) void k_agg(const uint16_t* __restrict__ H,
                                             const int* __restrict__ prow,
                                             const int* __restrict__ pairs2,
                                             const uint16_t* __restrict__ bias,
                                             const float* __restrict__ dis,
                                             void* __restrict__ OUT,
                                             const int* __restrict__ flag,
                                             int is_final){
  __shared__ int ebuf[4][96];    // [wave][64 live + 32 pad]
  int wave = threadIdx.x >> 6, lane = threadIdx.x & 63;
  int grp = lane >> 4, sl = lane & 15;
  if (lane >= 32) ebuf[wave][32 + lane] = PADROW;   // pad slots 64..95
  int n = blockIdx.x * 4 + wave;
  if (n >= NN) return;
  int beg = prow[n], end = prow[n + 1];

  float acc[8] = {0.f,0.f,0.f,0.f,0.f,0.f,0.f,0.f};
  for (int j0 = beg; j0 < end; j0 += 64){
    int cnt = min(64, end - j0);
    int r = (lane < cnt) ? pairs2[j0 + lane] : PADROW;
    ebuf[wave][lane] = r;
    int chunks = (cnt + 3) >> 2;
    int e0 = ebuf[wave][grp];
    int e1 = ebuf[wave][4 + grp];
    int e2 = ebuf[wave][8 + grp];
    uint32x4 v0 = *(const uint32x4*)(H + (ptrdiff_t)e0 * DD + sl * 8);
    uint32x4 v1 = *(const uint32x4*)(H + (ptrdiff_t)e1 * DD + sl * 8);
    uint32x4 v2 = *(const uint32x4*)(H + (ptrdiff_t)e2 * DD + sl * 8);
    for (int c = 0; c < chunks; c += 3){
      int n0 = ebuf[wave][(c + 3) * 4 + grp];
      int n1 = ebuf[wave][(c + 4) * 4 + grp];
      int n2 = ebuf[wave][(c + 5) * 4 + grp];
      uint32x4 w0 = *(const uint32x4*)(H + (ptrdiff_t)n0 * DD + sl * 8);
      uint32x4 w1 = *(const uint32x4*)(H + (ptrdiff_t)n1 * DD + sl * 8);
      uint32x4 w2 = *(const uint32x4*)(H + (ptrdiff_t)n2 * DD + sl * 8);
      ADD8(v0)
      ADD8(v1)
      ADD8(v2)
      v0 = w0; v1 = w1; v2 = w2;
    }
  }
  #pragma unroll
  for (int j = 0; j < 8; j++){
    acc[j] += __shfl_xor(acc[j], 16, 64);
    acc[j] += __shfl_xor(acc[j], 32, 64);
  }
  float dn = dis[n];
  uint32x4 bv = ((const uint32x4*)bias)[sl];
  float o0 = lrelu(fmaf(acc[0], dn, __uint_as_float(bv.x << 16)));
  float o1 = lrelu(fmaf(acc[1], dn, __uint_as_float(bv.x & 0xffff0000u)));
  float o2 = lrelu(fmaf(acc[2], dn, __uint_as_float(bv.y << 16)));
  float o3 = lrelu(fmaf(acc[3], dn, __uint_as_float(bv.y & 0xffff0000u)));
  float o4 = lrelu(fmaf(acc[4], dn, __uint_as_float(bv.z << 16)));
  float o5 = lrelu(fmaf(acc[5], dn, __uint_as_float(bv.z & 0xffff0000u)));
  float o6 = lrelu(fmaf(acc[6], dn, __uint_as_float(bv.w << 16)));
  float o7 = lrelu(fmaf(acc[7], dn, __uint_as_float(bv.w & 0xffff0000u)));
  if (is_final && flag[0]){
    float* orow = (float*)OUT + (size_t)n * DD + sl * 8;
    if (lane < 16){ floatx4 vv = {o0, o1, o2, o3}; ((floatx4*)orow)[0] = vv; }
    else if (lane < 32){ floatx4 vv = {o4, o5, o6, o7}; ((floatx4*)orow)[1] = vv; }
  } else if (lane < 16){
    uint32x4 pv;
    pv.x = (uint32_t)f2bf(o0) | ((uint32_t)f2bf(o1) << 16);
    pv.y = (uint32_t)f2bf(o2) | ((uint32_t)f2bf(o3) << 16);
    pv.z = (uint32_t)f2bf(o4) | ((uint32_t)f2bf(o5) << 16);
    pv.w = (uint32_t)f2bf(o6) | ((uint32_t)f2bf(o7) << 16);
    *(uint32x4*)((uint16_t*)OUT + (size_t)n * DD + sl * 8) = pv;
  }
}

extern "C" void kernel_launch(void* const* d_in, const int* in_sizes, int n_in,
                              void* d_out, int out_size, void* d_ws, size_t ws_size,
                              hipStream_t stream){
  const void* x  = d_in[0];
  const void* W1 = d_in[1];
  const void* b1 = d_in[2];
  const void* W2 = d_in[3];
  const void* b2 = d_in[4];
  const int* ei   = (const int*)d_in[5];
  const int* esrc = ei;
  const int* edst = ei + NE;

  char* ws = (char*)d_ws;
  float*    dis        = (float*)(ws + 0);                     // 400,000 B
  int*      prow       = (int*)(ws + 512ull * 1024);           // 400,004 B
  int*      flag       = (int*)(ws + 960ull * 1024);           // 4 B
  uint16_t* WT1        = (uint16_t*)(ws + 964ull * 1024);      // 32 KiB
  uint16_t* WT2        = (uint16_t*)(ws + 996ull * 1024);      // 32 KiB
  uint16_t* bb         = (uint16_t*)(ws + 1028ull * 1024);     // 512 B
  int*      gcur       = (int*)(ws + 1032ull * 1024);          // 25,024 B (padded)
  int*      pairs2     = (int*)(ws + 2048ull * 1024);          // 6.8 MB (bare ints)
  uint32_t* pairs      = (uint32_t*)(ws + 16320ull * 1024);    // 12.8 MB (dead pre-gemm1)
  uint16_t* hA         = (uint16_t*)(ws + 16384ull * 1024);    // 25.6 MB (aliases pairs;
                                                               //  pad row at hA-256*DD = ws+16320KiB)
  uint16_t* hB         = (uint16_t*)d_out;                     // scratch; gemm2 reads before agg2 writes

  k_init   <<<1, 512, 0, stream>>>((const uint32_t*)x, flag, gcur);
  k_scat1  <<<NBLKE + NWB, 512, 0, stream>>>(esrc, edst, gcur, pairs,
                                             W1, W2, b1, b2, WT1, WT2, bb, flag);
  k_bsort_a<<<NB, 512, 0, stream>>>(pairs, gcur, pairs2, prow, dis);
  k_bsort_b<<<NB, 512, 0, stream>>>(pairs, gcur, prow, pairs2);

  k_gemm<<<(NN + 63) / 64, 256, 0, stream>>>(x, WT1, hA, flag, 1, dis);
  k_agg <<<NN / 4, 256, 0, stream>>>(hA, prow, pairs2, bb, dis, hB, flag, 0);
  k_gemm<<<(NN + 63) / 64, 256, 0, stream>>>(hB, WT2, hA, flag, 0, dis);
  k_agg <<<NN / 4, 256, 0, stream>>>(hA, prow, pairs2, bb + 128, dis, d_out, flag, 1);
}

// Round 10
// 297.976 us; speedup vs baseline: 1.0123x; 1.0086x over previous
//
#include <hip/hip_runtime.h>
#include <hip/hip_bf16.h>
#include <stdint.h>

#define NN 100000
#define NE 1600000
#define NR (NE + NN)   // records incl. self-loops
#define DD 128
#define NEG 0.01f
#define NB 391        // buckets of 256 nodes (dst>>8); ceil(NN/256)
#define CAPSH 13      // 8192 pair slots per bucket (mean 4096 + 64 sigma)
#define NBLKE 391     // ceil(NE/4096) edge blocks (8 edges/thread @512)
#define NWB 65        // weight-pack rider blocks (33024/512 rounded up)
#define GPAD 16       // gcur stride in ints: one counter per 64B line
#define PADROW (-256) // pad record: zero row 256 rows before H base

typedef __attribute__((ext_vector_type(8))) short short8;
typedef __attribute__((ext_vector_type(4))) float floatx4;
typedef __attribute__((ext_vector_type(4))) uint32_t uint32x4;

__device__ __forceinline__ uint16_t f2bf(float f){
  uint32_t i = __float_as_uint(f);
  return (uint16_t)((i + 0x7FFFu + ((i >> 16) & 1u)) >> 16);  // RNE
}
__device__ __forceinline__ float lrelu(float x){ return fmaxf(x, NEG * x); }

// ---------------- init: dtype detect + zero padded bucket cursors -------------
__global__ __launch_bounds__(512) void k_init(const uint32_t* __restrict__ xw,
                                              int* __restrict__ flag,
                                              int* __restrict__ gcur){
  int t = threadIdx.x;
  for (int i = t; i < NB * GPAD; i += 512) gcur[i] = 0;
  if (t < 64){
    uint32_t w = xw[t];
    uint32_t e = (w >> 7) & 0xFFu;
    int plaus = (e >= 100u && e <= 134u) ? 1 : 0;
    unsigned long long b = __ballot(plaus);
    if (t == 0) flag[0] = (__popcll(b) >= 48) ? 0 : 1;
  }
}

// ---------------- bucket scatter (one pass) + weight-pack rider blocks --------
__global__ __launch_bounds__(512) void k_scat1(const int* __restrict__ src,
                                               const int* __restrict__ dst,
                                               int* __restrict__ gcur,
                                               uint32_t* __restrict__ pairs,
                                               const void* __restrict__ W1,
                                               const void* __restrict__ W2,
                                               const void* __restrict__ b1,
                                               const void* __restrict__ b2,
                                               uint16_t* __restrict__ WT1,
                                               uint16_t* __restrict__ WT2,
                                               uint16_t* __restrict__ bb,
                                               const int* __restrict__ flag){
  int t = threadIdx.x, b = blockIdx.x;
  if (b >= NBLKE){   // weight transpose + bias pack riders
    int j = (b - NBLKE) * 512 + t;
    int f = flag[0];
    if (j < 16384){
      int c = j >> 7, k = j & 127;
      WT1[j] = f ? f2bf(((const float*)W1)[k * DD + c])
                 : ((const uint16_t*)W1)[k * DD + c];
    } else if (j < 32768){
      int q = j - 16384;
      int c = q >> 7, k = q & 127;
      WT2[q] = f ? f2bf(((const float*)W2)[k * DD + c])
                 : ((const uint16_t*)W2)[k * DD + c];
    } else if (j < 33024){
      int q = j - 32768;
      const void* sp = (q < 128) ? b1 : b2;
      int i2 = q & 127;
      bb[q] = f ? f2bf(((const float*)sp)[i2]) : ((const uint16_t*)sp)[i2];
    }
    return;
  }
  __shared__ int lh[NB];
  if (t < NB) lh[t] = 0;
  __syncthreads();
  int ds[8], ss[8];
  #pragma unroll
  for (int i = 0; i < 8; i++){
    int e = b * 4096 + i * 512 + t;
    if (e < NE){
      ds[i] = dst[e]; ss[i] = src[e];
      atomicAdd(&lh[ds[i] >> 8], 1);
    } else ds[i] = -1;
  }
  __syncthreads();
  if (t < NB){
    int c = lh[t];
    int base = c ? atomicAdd(&gcur[t * GPAD], c) : 0;
    lh[t] = (t << CAPSH) + base;        // block-local cursor = global slot
  }
  __syncthreads();
  #pragma unroll
  for (int i = 0; i < 8; i++){
    if (ds[i] >= 0){
      int bkt = ds[i] >> 8;
      int pos = atomicAdd(&lh[bkt], 1);
      if (pos < ((bkt + 1) << CAPSH))   // cap guard (never fires on 16-sigma input)
        pairs[pos] = ((uint32_t)(ds[i] & 255) << 24) | (uint32_t)ss[i];
    }
  }
}

// ---------------- fused bsort: counts+scan -> prow/dis/self, then re-scatter --
// Phase B needs only THIS bucket's cursors, which phase A already has in LDS
// (the old a/b split re-derived them from global prow for no reason). Second
// pairs read is L2-hot (same 16KB slice read moments earlier).
__global__ __launch_bounds__(512) void k_bsort(const uint32_t* __restrict__ pairs,
                                               const int* __restrict__ gcur,
                                               int* __restrict__ pairs2,
                                               int* __restrict__ prow,
                                               float* __restrict__ dis){
  __shared__ int sg[512];
  __shared__ int lcnt[256], sm[256], cur[256];
  __shared__ int s_pe;
  int t = threadIdx.x, bkt = blockIdx.x, n0 = bkt << 8;
  int v0 = (t < NB) ? gcur[t * GPAD] : 0;
  sg[t] = v0;
  __syncthreads();
  for (int s = 1; s < 512; s <<= 1){
    int add = (t >= s) ? sg[t - s] : 0;
    __syncthreads();
    sg[t] += add;
    __syncthreads();
  }
  if (t == bkt) s_pe = sg[t] - v0;      // edges in buckets before this one
  if (t < 256) lcnt[t] = 0;
  __syncthreads();
  int cnt = gcur[bkt * GPAD];
  int begE = bkt << CAPSH;
  for (int i = t; i < cnt; i += 512)
    atomicAdd(&lcnt[pairs[begE + i] >> 24], 1);
  __syncthreads();
  int inb = (n0 + t < NN) ? 1 : 0;
  int v = (t < 256) ? lcnt[t] + inb : 0;
  if (t < 256) sm[t] = v;
  __syncthreads();
  for (int s = 1; s < 256; s <<= 1){
    int add = (t < 256 && t >= s) ? sm[t - s] : 0;
    __syncthreads();
    if (t < 256) sm[t] += add;
    __syncthreads();
  }
  if (t < 256){
    int n = n0 + t;
    int begS = s_pe + n0;               // + one self slot per preceding node
    int excl = sm[t] - v;
    if (n <= NN) prow[n] = begS + excl; // n==NN (bkt 390, t=160) -> prow[NN]=NR
    cur[t] = begS + excl + 1;           // first edge slot (after self)
    if (n < NN){
      dis[n] = rsqrtf((float)(lcnt[t] + 1));
      pairs2[begS + excl] = n;          // self record: bare index
    }
  }
  __syncthreads();
  // phase B: re-scatter bare src into CSR order (bucket-local cursors in LDS)
  for (int i = t; i < cnt; i += 512){
    uint32_t u = pairs[begE + i];
    int li = u >> 24;
    int pos = atomicAdd(&cur[li], 1);
    pairs2[pos] = (int)(u & 0xFFFFFFu);
  }
}

__device__ __forceinline__ short8 ldcvt(const float* __restrict__ p){
  floatx4 u = ((const floatx4*)p)[0], v = ((const floatx4*)p)[1];
  short8 r;
  r[0] = (short)f2bf(u.x); r[1] = (short)f2bf(u.y);
  r[2] = (short)f2bf(u.z); r[3] = (short)f2bf(u.w);
  r[4] = (short)f2bf(v.x); r[5] = (short)f2bf(v.y);
  r[6] = (short)f2bf(v.z); r[7] = (short)f2bf(v.w);
  return r;
}

// ---------------- GEMM: Hs = dn[row] * (X * W) (pre-scaled rows) --------------
// Block 0 zeroes the pad row at H - 256*DD so agg pipeline over-reads add 0.
__global__ __launch_bounds__(256) void k_gemm(const void* __restrict__ X,
                                              const uint16_t* __restrict__ WT,
                                              uint16_t* __restrict__ H,
                                              const int* __restrict__ flag,
                                              int xf32,
                                              const float* __restrict__ dis){
  __shared__ uint16_t lwt[128 * 136];   // +8 shorts pad -> 2-way bank alias (free)
  int t = threadIdx.x;
  if (blockIdx.x == 0 && t < 16){
    uint32x4 z = {0u, 0u, 0u, 0u};
    *(uint32x4*)(H + (ptrdiff_t)PADROW * DD + t * 8) = z;
  }
  const uint32_t* wt32 = (const uint32_t*)WT;
  #pragma unroll
  for (int i = 0; i < 32; i++){
    int uidx = t + 256 * i;
    uint32_t w2 = wt32[uidx];
    int el = uidx * 2;
    int c = el >> 7, k = el & 127;
    *(uint32_t*)&lwt[c * 136 + k] = w2;
  }
  __syncthreads();

  int wave = t >> 6, lane = t & 63;
  int m = lane & 15, q = lane >> 4;
  int rowbase = blockIdx.x * 64 + wave * 16;
  int ar = rowbase + m;
  if (ar >= NN) ar = 0;
  short8 a0, a1, a2, a3;
  if (xf32 && flag[0]){
    const float* xr = (const float*)X + (size_t)ar * DD;
    a0 = ldcvt(xr + q * 8);        a1 = ldcvt(xr + (q + 4) * 8);
    a2 = ldcvt(xr + (q + 8) * 8);  a3 = ldcvt(xr + (q + 12) * 8);
  } else {
    const short8* xrow = (const short8*)((const uint16_t*)X + (size_t)ar * DD);
    a0 = xrow[q]; a1 = xrow[q + 4]; a2 = xrow[q + 8]; a3 = xrow[q + 12];
  }
  float dnr[4];
  #pragma unroll
  for (int r = 0; r < 4; r++){
    int row = rowbase + q * 4 + r;
    dnr[r] = dis[(row < NN) ? row : 0];
  }

  #pragma unroll
  for (int nt = 0; nt < 8; nt++){
    int c = nt * 16 + m;
    const uint16_t* bp = &lwt[c * 136 + q * 8];
    floatx4 acc = {0.f, 0.f, 0.f, 0.f};
    acc = __builtin_amdgcn_mfma_f32_16x16x32_bf16(a0, *(const short8*)(bp +  0), acc, 0, 0, 0);
    acc = __builtin_amdgcn_mfma_f32_16x16x32_bf16(a1, *(const short8*)(bp + 32), acc, 0, 0, 0);
    acc = __builtin_amdgcn_mfma_f32_16x16x32_bf16(a2, *(const short8*)(bp + 64), acc, 0, 0, 0);
    acc = __builtin_amdgcn_mfma_f32_16x16x32_bf16(a3, *(const short8*)(bp + 96), acc, 0, 0, 0);
    #pragma unroll
    for (int r = 0; r < 4; r++){
      int row = rowbase + q * 4 + r;
      if (row < NN) H[(size_t)row * DD + c] = f2bf(acc[r] * dnr[r]);
    }
  }
}

#define ADD8(VA)                                          \
  acc[0] += __uint_as_float(VA.x << 16);                  \
  acc[1] += __uint_as_float(VA.x & 0xffff0000u);          \
  acc[2] += __uint_as_float(VA.y << 16);                  \
  acc[3] += __uint_as_float(VA.y & 0xffff0000u);          \
  acc[4] += __uint_as_float(VA.z << 16);                  \
  acc[5] += __uint_as_float(VA.z & 0xffff0000u);          \
  acc[6] += __uint_as_float(VA.w << 16);                  \
  acc[7] += __uint_as_float(VA.w & 0xffff0000u);

// ---------------- fused agg1 + gemm2: 16 waves x ONE node/wave ----------------
// Gather code bit-identical to the frozen 3.9 TB/s recipe (R7 lesson: serial
// nodes/wave drain the pipeline; here each wave owns exactly one node, as in
// k_agg). lrelu'd layer-1 rows -> 16x128 LDS tile -> MFMA epilogue computes
// Hs2 = dn_row * (h*W2) directly (B-frags from L2-resident WT2), deleting the
// h round-trip (51 MB) and the gemm2 dispatch.
__global__ __launch_bounds__(1024) void k_aggg(const uint16_t* __restrict__ H,
                                               const int* __restrict__ prow,
                                               const int* __restrict__ pairs2,
                                               const uint16_t* __restrict__ bias,
                                               const float* __restrict__ dis,
                                               const uint16_t* __restrict__ WT2,
                                               uint16_t* __restrict__ H2){
  __shared__ int ebuf[16][96];          // [wave][64 live + 32 pad]
  __shared__ uint16_t hrow[16 * 136];   // 16x128 A-tile (stride 136 for align)
  int wave = threadIdx.x >> 6, lane = threadIdx.x & 63;
  int grp = lane >> 4, sl = lane & 15;
  if (lane >= 32) ebuf[wave][32 + lane] = PADROW;
  int tile = blockIdx.x << 4;           // 6250 * 16 == NN, no tail
  int n = tile + wave;
  if (blockIdx.x == 0 && wave == 15 && lane < 16){   // zero H2 pad row
    uint32x4 z = {0u, 0u, 0u, 0u};
    *(uint32x4*)(H2 + (ptrdiff_t)PADROW * DD + lane * 8) = z;
  }
  int beg = prow[n], end = prow[n + 1];

  float acc[8] = {0.f,0.f,0.f,0.f,0.f,0.f,0.f,0.f};
  for (int j0 = beg; j0 < end; j0 += 64){
    int cnt = min(64, end - j0);
    int r = (lane < cnt) ? pairs2[j0 + lane] : PADROW;
    ebuf[wave][lane] = r;
    int chunks = (cnt + 3) >> 2;
    int e0 = ebuf[wave][grp];
    int e1 = ebuf[wave][4 + grp];
    int e2 = ebuf[wave][8 + grp];
    uint32x4 v0 = *(const uint32x4*)(H + (ptrdiff_t)e0 * DD + sl * 8);
    uint32x4 v1 = *(const uint32x4*)(H + (ptrdiff_t)e1 * DD + sl * 8);
    uint32x4 v2 = *(const uint32x4*)(H + (ptrdiff_t)e2 * DD + sl * 8);
    for (int c = 0; c < chunks; c += 3){
      int n0 = ebuf[wave][(c + 3) * 4 + grp];
      int n1 = ebuf[wave][(c + 4) * 4 + grp];
      int n2 = ebuf[wave][(c + 5) * 4 + grp];
      uint32x4 w0 = *(const uint32x4*)(H + (ptrdiff_t)n0 * DD + sl * 8);
      uint32x4 w1 = *(const uint32x4*)(H + (ptrdiff_t)n1 * DD + sl * 8);
      uint32x4 w2 = *(const uint32x4*)(H + (ptrdiff_t)n2 * DD + sl * 8);
      ADD8(v0)
      ADD8(v1)
      ADD8(v2)
      v0 = w0; v1 = w1; v2 = w2;
    }
  }
  #pragma unroll
  for (int j = 0; j < 8; j++){
    acc[j] += __shfl_xor(acc[j], 16, 64);
    acc[j] += __shfl_xor(acc[j], 32, 64);
  }
  float dn = dis[n];
  uint32x4 bv = ((const uint32x4*)bias)[sl];
  float o0 = lrelu(fmaf(acc[0], dn, __uint_as_float(bv.x << 16)));
  float o1 = lrelu(fmaf(acc[1], dn, __uint_as_float(bv.x & 0xffff0000u)));
  float o2 = lrelu(fmaf(acc[2], dn, __uint_as_float(bv.y << 16)));
  float o3 = lrelu(fmaf(acc[3], dn, __uint_as_float(bv.y & 0xffff0000u)));
  float o4 = lrelu(fmaf(acc[4], dn, __uint_as_float(bv.z << 16)));
  float o5 = lrelu(fmaf(acc[5], dn, __uint_as_float(bv.z & 0xffff0000u)));
  float o6 = lrelu(fmaf(acc[6], dn, __uint_as_float(bv.w << 16)));
  float o7 = lrelu(fmaf(acc[7], dn, __uint_as_float(bv.w & 0xffff0000u)));
  if (lane < 16){
    uint32x4 pv;
    pv.x = (uint32_t)f2bf(o0) | ((uint32_t)f2bf(o1) << 16);
    pv.y = (uint32_t)f2bf(o2) | ((uint32_t)f2bf(o3) << 16);
    pv.z = (uint32_t)f2bf(o4) | ((uint32_t)f2bf(o5) << 16);
    pv.w = (uint32_t)f2bf(o6) | ((uint32_t)f2bf(o7) << 16);
    *(uint32x4*)&hrow[wave * 136 + sl * 8] = pv;
  }
  __syncthreads();

  // GEMM epilogue: Hs2[16x128] = dn_row * (hrow * W2); waves 0..7, 1 col-tile each.
  if (wave < 8){
    int m = lane & 15, q = lane >> 4;
    short8 a0 = *(const short8*)&hrow[m * 136 + q * 8];
    short8 a1 = *(const short8*)&hrow[m * 136 + (q + 4) * 8];
    short8 a2 = *(const short8*)&hrow[m * 136 + (q + 8) * 8];
    short8 a3 = *(const short8*)&hrow[m * 136 + (q + 12) * 8];
    int c = wave * 16 + m;
    const uint16_t* bp = WT2 + c * DD + q * 8;
    floatx4 a2c = {0.f, 0.f, 0.f, 0.f};
    a2c = __builtin_amdgcn_mfma_f32_16x16x32_bf16(a0, *(const short8*)(bp +  0), a2c, 0, 0, 0);
    a2c = __builtin_amdgcn_mfma_f32_16x16x32_bf16(a1, *(const short8*)(bp + 32), a2c, 0, 0, 0);
    a2c = __builtin_amdgcn_mfma_f32_16x16x32_bf16(a2, *(const short8*)(bp + 64), a2c, 0, 0, 0);
    a2c = __builtin_amdgcn_mfma_f32_16x16x32_bf16(a3, *(const short8*)(bp + 96), a2c, 0, 0, 0);
    #pragma unroll
    for (int r = 0; r < 4; r++){
      int row = tile + q * 4 + r;
      H2[(size_t)row * DD + c] = f2bf(a2c[r] * dis[row]);
    }
  }
}

// ---------------- final aggregation (frozen recipe), bare-int records ---------
__global__ __launch_bounds__(256) void k_agg(const uint16_t* __restrict__ H,
                                             const int* __restrict__ prow,
                                             const int* __restrict__ pairs2,
                                             const uint16_t* __restrict__ bias,
                                             const float* __restrict__ dis,
                                             void* __restrict__ OUT,
                                             const int* __restrict__ flag,
                                             int is_final){
  __shared__ int ebuf[4][96];    // [wave][64 live + 32 pad]
  int wave = threadIdx.x >> 6, lane = threadIdx.x & 63;
  int grp = lane >> 4, sl = lane & 15;
  if (lane >= 32) ebuf[wave][32 + lane] = PADROW;   // pad slots 64..95
  int n = blockIdx.x * 4 + wave;
  if (n >= NN) return;
  int beg = prow[n], end = prow[n + 1];

  float acc[8] = {0.f,0.f,0.f,0.f,0.f,0.f,0.f,0.f};
  for (int j0 = beg; j0 < end; j0 += 64){
    int cnt = min(64, end - j0);
    int r = (lane < cnt) ? pairs2[j0 + lane] : PADROW;
    ebuf[wave][lane] = r;
    int chunks = (cnt + 3) >> 2;
    int e0 = ebuf[wave][grp];
    int e1 = ebuf[wave][4 + grp];
    int e2 = ebuf[wave][8 + grp];
    uint32x4 v0 = *(const uint32x4*)(H + (ptrdiff_t)e0 * DD + sl * 8);
    uint32x4 v1 = *(const uint32x4*)(H + (ptrdiff_t)e1 * DD + sl * 8);
    uint32x4 v2 = *(const uint32x4*)(H + (ptrdiff_t)e2 * DD + sl * 8);
    for (int c = 0; c < chunks; c += 3){
      int n0 = ebuf[wave][(c + 3) * 4 + grp];
      int n1 = ebuf[wave][(c + 4) * 4 + grp];
      int n2 = ebuf[wave][(c + 5) * 4 + grp];
      uint32x4 w0 = *(const uint32x4*)(H + (ptrdiff_t)n0 * DD + sl * 8);
      uint32x4 w1 = *(const uint32x4*)(H + (ptrdiff_t)n1 * DD + sl * 8);
      uint32x4 w2 = *(const uint32x4*)(H + (ptrdiff_t)n2 * DD + sl * 8);
      ADD8(v0)
      ADD8(v1)
      ADD8(v2)
      v0 = w0; v1 = w1; v2 = w2;
    }
  }
  #pragma unroll
  for (int j = 0; j < 8; j++){
    acc[j] += __shfl_xor(acc[j], 16, 64);
    acc[j] += __shfl_xor(acc[j], 32, 64);
  }
  float dn = dis[n];
  uint32x4 bv = ((const uint32x4*)bias)[sl];
  float o0 = lrelu(fmaf(acc[0], dn, __uint_as_float(bv.x << 16)));
  float o1 = lrelu(fmaf(acc[1], dn, __uint_as_float(bv.x & 0xffff0000u)));
  float o2 = lrelu(fmaf(acc[2], dn, __uint_as_float(bv.y << 16)));
  float o3 = lrelu(fmaf(acc[3], dn, __uint_as_float(bv.y & 0xffff0000u)));
  float o4 = lrelu(fmaf(acc[4], dn, __uint_as_float(bv.z << 16)));
  float o5 = lrelu(fmaf(acc[5], dn, __uint_as_float(bv.z & 0xffff0000u)));
  float o6 = lrelu(fmaf(acc[6], dn, __uint_as_float(bv.w << 16)));
  float o7 = lrelu(fmaf(acc[7], dn, __uint_as_float(bv.w & 0xffff0000u)));
  if (is_final && flag[0]){
    float* orow = (float*)OUT + (size_t)n * DD + sl * 8;
    if (lane < 16){ floatx4 vv = {o0, o1, o2, o3}; ((floatx4*)orow)[0] = vv; }
    else if (lane < 32){ floatx4 vv = {o4, o5, o6, o7}; ((floatx4*)orow)[1] = vv; }
  } else if (lane < 16){
    uint32x4 pv;
    pv.x = (uint32_t)f2bf(o0) | ((uint32_t)f2bf(o1) << 16);
    pv.y = (uint32_t)f2bf(o2) | ((uint32_t)f2bf(o3) << 16);
    pv.z = (uint32_t)f2bf(o4) | ((uint32_t)f2bf(o5) << 16);
    pv.w = (uint32_t)f2bf(o6) | ((uint32_t)f2bf(o7) << 16);
    *(uint32x4*)((uint16_t*)OUT + (size_t)n * DD + sl * 8) = pv;
  }
}

extern "C" void kernel_launch(void* const* d_in, const int* in_sizes, int n_in,
                              void* d_out, int out_size, void* d_ws, size_t ws_size,
                              hipStream_t stream){
  const void* x  = d_in[0];
  const void* W1 = d_in[1];
  const void* b1 = d_in[2];
  const void* W2 = d_in[3];
  const void* b2 = d_in[4];
  const int* ei   = (const int*)d_in[5];
  const int* esrc = ei;
  const int* edst = ei + NE;

  char* ws = (char*)d_ws;
  float*    dis        = (float*)(ws + 0);                     // 400,000 B
  int*      prow       = (int*)(ws + 512ull * 1024);           // 400,004 B
  int*      flag       = (int*)(ws + 960ull * 1024);           // 4 B
  uint16_t* WT1        = (uint16_t*)(ws + 964ull * 1024);      // 32 KiB
  uint16_t* WT2        = (uint16_t*)(ws + 996ull * 1024);      // 32 KiB
  uint16_t* bb         = (uint16_t*)(ws + 1028ull * 1024);     // 512 B
  int*      gcur       = (int*)(ws + 1032ull * 1024);          // 25,024 B (padded)
  int*      pairs2     = (int*)(ws + 2048ull * 1024);          // 6.8 MB (bare ints)
  uint32_t* pairs      = (uint32_t*)(ws + 16320ull * 1024);    // 12.8 MB (dead pre-gemm1)
  uint16_t* hA         = (uint16_t*)(ws + 16384ull * 1024);    // 25.6 MB (aliases pairs tail;
                                                               //  pad row at ws+16320KiB)

  k_init <<<1, 512, 0, stream>>>((const uint32_t*)x, flag, gcur);
  k_scat1<<<NBLKE + NWB, 512, 0, stream>>>(esrc, edst, gcur, pairs,
                                           W1, W2, b1, b2, WT1, WT2, bb, flag);
  k_bsort<<<NB, 512, 0, stream>>>(pairs, gcur, pairs2, prow, dis);

  if (in_sizes[0] == (int)(NN * DD * 4)){
    // f32 input (bench case): fused path. Hs1 lives in d_out (51.2 MB f32 out
    // buffer; 64KB pad headroom at d_out+0, zeroed by gemm1 block 0). H2 = hA.
    uint16_t* hs1 = (uint16_t*)d_out + 256 * DD;
    k_gemm<<<(NN + 63) / 64, 256, 0, stream>>>(x, WT1, hs1, flag, 1, dis);
    k_aggg<<<NN / 16, 1024, 0, stream>>>(hs1, prow, pairs2, bb, dis, WT2, hA);
    k_agg <<<NN / 4, 256, 0, stream>>>(hA, prow, pairs2, bb + 128, dis, d_out, flag, 1);
  } else {
    // fallback: exact R8 schedule (no pad headroom assumptions on d_out)
    uint16_t* hB = (uint16_t*)d_out;
    k_gemm<<<(NN + 63) / 64, 256, 0, stream>>>(x, WT1, hA, flag, 1, dis);
    k_agg <<<NN / 4, 256, 0, stream>>>(hA, prow, pairs2, bb, dis, hB, flag, 0);
    k_gemm<<<(NN + 63) / 64, 256, 0, stream>>>(hB, WT2, hA, flag, 0, dis);
    k_agg <<<NN / 4, 256, 0, stream>>>(hA, prow, pairs2, bb + 128, dis, d_out, flag, 1);
  }
}